// Round 19
// baseline (125.129 us; speedup 1.0000x reference)
//
#include <hip/hip_runtime.h>
#include <hip/hip_fp16.h>

#define N_NODES 40000
#define N_EDGES 640000
#define D 128
#define ELLW 48        // max degree headroom (Binomial max ~35); multiple of 16
#define SENT 40000     // sentinel node index -> zeroed feature row

typedef __attribute__((ext_vector_type(8))) short short8;
typedef __attribute__((ext_vector_type(4))) float f32x4;

__device__ __forceinline__ unsigned short f2bf(float f) {
  unsigned int u = __float_as_uint(f);
  u += 0x7fffu + ((u >> 16) & 1u);   // round-to-nearest-even
  return (unsigned short)(u >> 16);
}

// ---------------- prep: deg zero + x->bf16 + x->fp16 + W->bf16 + ell sentinel -----
// blocks [0,5000): x converts (1,280,000 float4 groups) + deg zero
// blocks [5000,5064): W converts; block 5000 also zeroes all sentinel rows
// blocks [5064,6002): fill ell with SENT (240,000 uint4)
__global__ void k_prep(const float* __restrict__ x, unsigned short* __restrict__ xb,
                       unsigned short* __restrict__ hb,
                       __half* __restrict__ xh, __half* __restrict__ hh,
                       int* __restrict__ deg, unsigned short* __restrict__ ell,
                       const float* __restrict__ w0, const float* __restrict__ w1,
                       const float* __restrict__ w2, const float* __restrict__ w3,
                       unsigned short* __restrict__ o0, unsigned short* __restrict__ o1,
                       unsigned short* __restrict__ o2, unsigned short* __restrict__ o3) {
  int b = blockIdx.x;
  int tid = threadIdx.x;
  if (b < 5000) {                       // x converts (+ deg zero)
    int i = b * 256 + tid;              // i < 1,280,000 exactly
    if (i < N_NODES / 4) ((int4*)deg)[i] = make_int4(0, 0, 0, 0);
    float4 v = ((const float4*)x)[i];
    unsigned int lo = (unsigned int)f2bf(v.x) | ((unsigned int)f2bf(v.y) << 16);
    unsigned int hi = (unsigned int)f2bf(v.z) | ((unsigned int)f2bf(v.w) << 16);
    ((uint2*)xb)[i] = make_uint2(lo, hi);
    __half2 h0 = __floats2half2_rn(v.x, v.y);
    __half2 h1 = __floats2half2_rn(v.z, v.w);
    ((uint2*)xh)[i] = make_uint2(*(unsigned int*)&h0, *(unsigned int*)&h1);
  } else if (b < 5064) {                // W converts: 4 * 4096 float4 groups
    if (b == 5000) {                    // zero sentinel rows (each 256B = 64 uint)
      if (tid < 64)       ((unsigned int*)(xb + (size_t)SENT * D))[tid] = 0u;
      else if (tid < 128) ((unsigned int*)(hb + (size_t)SENT * D))[tid - 64] = 0u;
      else if (tid < 192) ((unsigned int*)(xh + (size_t)SENT * D))[tid - 128] = 0u;
      else                ((unsigned int*)(hh + (size_t)SENT * D))[tid - 192] = 0u;
    }
    int i = (b - 5000) * 256 + tid;
    int m = i >> 12, j = i & 4095;
    const float* s = (m == 0) ? w0 : (m == 1) ? w1 : (m == 2) ? w2 : w3;
    unsigned short* o = (m == 0) ? o0 : (m == 1) ? o1 : (m == 2) ? o2 : o3;
    float4 v = ((const float4*)s)[j];
    unsigned int lo = (unsigned int)f2bf(v.x) | ((unsigned int)f2bf(v.y) << 16);
    unsigned int hi = (unsigned int)f2bf(v.z) | ((unsigned int)f2bf(v.w) << 16);
    ((uint2*)o)[j] = make_uint2(lo, hi);
  } else {                              // ell sentinel fill: 240,000 uint4
    int i = (b - 5064) * 256 + tid;
    if (i < N_NODES * ELLW / 8) {
      unsigned int sv = (SENT & 0xffffu) | ((unsigned int)SENT << 16);
      uint4 q; q.x = sv; q.y = sv; q.z = sv; q.w = sv;
      ((uint4*)ell)[i] = q;
    }
  }
}

// ---------------- ELL build: count + fill in ONE kernel (no scan) ----------------
__global__ void k_fillell(const int* __restrict__ src, const int* __restrict__ dst,
                          int* __restrict__ deg, unsigned short* __restrict__ ell) {
  int e = blockIdx.x * 256 + threadIdx.x;
  if (e < N_EDGES) {
    int d = dst[e];
    int pos = atomicAdd(&deg[d], 1);
    if (pos < ELLW) ell[(size_t)d * ELLW + pos] = (unsigned short)src[e];
  }
}

// ---------------- aggregation v10: transposed + packed fp16 accumulate ------------
// r15 structure (8 lanes/node, 8 nodes/wave, 5000 waves, zero cross-lane reduce),
// but tables are fp16 and accumulation uses v_pk_add_f16 (__hadd2): per row per
// lane 2 loads + 8 pk_adds vs fp8's 1 load + 24 VALU -> ~2.5x less VALU in the
// hot loop (agg was VALU-decode-bound after r15). 2 neighbors/iter = 4 loads in
// flight (16 VGPRs - stays under the VGPR=64 occupancy cliff; r17 lesson).
__global__ void k_agg(const uint4* __restrict__ th, const int* __restrict__ deg,
                      const unsigned short* __restrict__ ell, uint4* __restrict__ mean4) {
  int node = blockIdx.x * 32 + (threadIdx.x >> 3);   // 32 nodes per 256-thread block
  int s = threadIdx.x & 7;                           // owns cols [16s,16s+16)
  int d = deg[node];
  int cnt = d < ELLW ? d : ELLW;
  int cntp = (cnt + 1) & ~1;                         // sentinel-padded to mult of 2
  const unsigned short* row = ell + (size_t)node * ELLW;
  __half2 acc[8];
#pragma unroll
  for (int i = 0; i < 8; ++i) acc[i] = __floats2half2_rn(0.f, 0.f);
  for (int e = 0; e < cntp; e += 2) {
    int i0 = row[e], i1 = row[e + 1];
    uint4 va0 = th[(size_t)i0 * 16 + s * 2];         // 4 independent 16B loads
    uint4 vb0 = th[(size_t)i0 * 16 + s * 2 + 1];
    uint4 va1 = th[(size_t)i1 * 16 + s * 2];
    uint4 vb1 = th[(size_t)i1 * 16 + s * 2 + 1];
    acc[0] = __hadd2(acc[0], *(const __half2*)&va0.x);
    acc[1] = __hadd2(acc[1], *(const __half2*)&va0.y);
    acc[2] = __hadd2(acc[2], *(const __half2*)&va0.z);
    acc[3] = __hadd2(acc[3], *(const __half2*)&va0.w);
    acc[4] = __hadd2(acc[4], *(const __half2*)&vb0.x);
    acc[5] = __hadd2(acc[5], *(const __half2*)&vb0.y);
    acc[6] = __hadd2(acc[6], *(const __half2*)&vb0.z);
    acc[7] = __hadd2(acc[7], *(const __half2*)&vb0.w);
    acc[0] = __hadd2(acc[0], *(const __half2*)&va1.x);
    acc[1] = __hadd2(acc[1], *(const __half2*)&va1.y);
    acc[2] = __hadd2(acc[2], *(const __half2*)&va1.z);
    acc[3] = __hadd2(acc[3], *(const __half2*)&va1.w);
    acc[4] = __hadd2(acc[4], *(const __half2*)&vb1.x);
    acc[5] = __hadd2(acc[5], *(const __half2*)&vb1.y);
    acc[6] = __hadd2(acc[6], *(const __half2*)&vb1.z);
    acc[7] = __hadd2(acc[7], *(const __half2*)&vb1.w);
  }
  float inv = 1.0f / (float)(d > 1 ? d : 1);
  float a[16];
#pragma unroll
  for (int i = 0; i < 8; ++i) {
    float2 f = __half22float2(acc[i]);
    a[2 * i] = f.x * inv;
    a[2 * i + 1] = f.y * inv;
  }
  uint4 o0, o1;
  o0.x = (unsigned int)f2bf(a[0]) | ((unsigned int)f2bf(a[1]) << 16);
  o0.y = (unsigned int)f2bf(a[2]) | ((unsigned int)f2bf(a[3]) << 16);
  o0.z = (unsigned int)f2bf(a[4]) | ((unsigned int)f2bf(a[5]) << 16);
  o0.w = (unsigned int)f2bf(a[6]) | ((unsigned int)f2bf(a[7]) << 16);
  o1.x = (unsigned int)f2bf(a[8]) | ((unsigned int)f2bf(a[9]) << 16);
  o1.y = (unsigned int)f2bf(a[10]) | ((unsigned int)f2bf(a[11]) << 16);
  o1.z = (unsigned int)f2bf(a[12]) | ((unsigned int)f2bf(a[13]) << 16);
  o1.w = (unsigned int)f2bf(a[14]) | ((unsigned int)f2bf(a[15]) << 16);
  mean4[(size_t)node * 16 + s * 2] = o0;
  mean4[(size_t)node * 16 + s * 2 + 1] = o1;
}

// ---------------- dual bf16-MFMA GEMM: 1 wave = 32 rows, no LDS, no barrier -------
// relu path additionally emits the fp16 copy of h for the next layer's gather.
__global__ __launch_bounds__(64) void k_gemm(
    const unsigned short* __restrict__ Al, const unsigned short* __restrict__ Ar,
    const unsigned short* __restrict__ Wl, const unsigned short* __restrict__ Wr,
    const float* __restrict__ bias,
    unsigned short* __restrict__ out_bf, __half* __restrict__ out_h,
    float* __restrict__ out_f, int relu_bf16) {
  const int lane = threadIdx.x;
  const int m0 = blockIdx.x * 32;
  const int ml = lane & 15;      // row within m-subtile / col within n-tile
  const int kg = lane >> 4;      // k-group of 8
  const unsigned short* al0 = Al + (size_t)(m0 + ml) * 128 + kg * 8;
  const unsigned short* ar0 = Ar + (size_t)(m0 + ml) * 128 + kg * 8;
  const unsigned short* al1 = al0 + 16 * 128;
  const unsigned short* ar1 = ar0 + 16 * 128;
  const unsigned short* wl_p = Wl + (size_t)ml * 128 + kg * 8;
  const unsigned short* wr_p = Wr + (size_t)ml * 128 + kg * 8;

  f32x4 acc[2][8];
#pragma unroll
  for (int mt = 0; mt < 2; ++mt)
#pragma unroll
    for (int nt = 0; nt < 8; ++nt) acc[mt][nt] = 0;

#pragma unroll
  for (int kt = 0; kt < 4; ++kt) {
    short8 a0l = *(const short8*)(al0 + kt * 32);
    short8 a0r = *(const short8*)(ar0 + kt * 32);
    short8 a1l = *(const short8*)(al1 + kt * 32);
    short8 a1r = *(const short8*)(ar1 + kt * 32);
#pragma unroll
    for (int nt = 0; nt < 8; ++nt) {
      short8 b_l = *(const short8*)(wl_p + nt * 2048 + kt * 32);
      short8 b_r = *(const short8*)(wr_p + nt * 2048 + kt * 32);
      acc[0][nt] = __builtin_amdgcn_mfma_f32_16x16x32_bf16(a0l, b_l, acc[0][nt], 0, 0, 0);
      acc[0][nt] = __builtin_amdgcn_mfma_f32_16x16x32_bf16(a0r, b_r, acc[0][nt], 0, 0, 0);
      acc[1][nt] = __builtin_amdgcn_mfma_f32_16x16x32_bf16(a1l, b_l, acc[1][nt], 0, 0, 0);
      acc[1][nt] = __builtin_amdgcn_mfma_f32_16x16x32_bf16(a1r, b_r, acc[1][nt], 0, 0, 0);
    }
  }

#pragma unroll
  for (int mt = 0; mt < 2; ++mt) {
    const int orow = m0 + mt * 16 + kg * 4;   // + r
#pragma unroll
    for (int nt = 0; nt < 8; ++nt) {
      int col = nt * 16 + ml;
      float b = bias[col];
#pragma unroll
      for (int r = 0; r < 4; ++r) {
        float o = acc[mt][nt][r] + b;
        if (relu_bf16) {
          o = fmaxf(o, 0.f);
          out_bf[(size_t)(orow + r) * 128 + col] = f2bf(o);
          out_h[(size_t)(orow + r) * 128 + col] = __float2half(o);
        } else {
          out_f[(size_t)(orow + r) * 128 + col] = o;
        }
      }
    }
  }
}

extern "C" void kernel_launch(void* const* d_in, const int* in_sizes, int n_in,
                              void* d_out, int out_size, void* d_ws, size_t ws_size,
                              hipStream_t stream) {
  const float* x   = (const float*)d_in[0];
  const int*   ei  = (const int*)d_in[1];
  const float* W1l = (const float*)d_in[2];
  const float* b1l = (const float*)d_in[3];
  const float* W1r = (const float*)d_in[4];
  const float* W2l = (const float*)d_in[5];
  const float* b2l = (const float*)d_in[6];
  const float* W2r = (const float*)d_in[7];
  const int* srcp = ei;
  const int* dstp = ei + N_EDGES;

  char* ws = (char*)d_ws;
  size_t off = 0;
  auto alloc = [&](size_t bytes) {
    void* p = ws + off;
    off = (off + bytes + 255) & ~(size_t)255;
    return p;
  };
  int* deg             = (int*)alloc((size_t)N_NODES * 4);
  unsigned short* ell  = (unsigned short*)alloc((size_t)N_NODES * ELLW * 2);
  unsigned short* w1lb = (unsigned short*)alloc((size_t)D * D * 2);
  unsigned short* w1rb = (unsigned short*)alloc((size_t)D * D * 2);
  unsigned short* w2lb = (unsigned short*)alloc((size_t)D * D * 2);
  unsigned short* w2rb = (unsigned short*)alloc((size_t)D * D * 2);
  unsigned short* xb   = (unsigned short*)alloc((size_t)(N_NODES + 1) * D * 2); // + sentinel
  unsigned short* mb   = (unsigned short*)alloc((size_t)N_NODES * D * 2);
  unsigned short* hb   = (unsigned short*)alloc((size_t)(N_NODES + 1) * D * 2); // + sentinel
  __half* xh           = (__half*)alloc((size_t)(N_NODES + 1) * D * 2);         // fp16 x table
  __half* hh           = (__half*)alloc((size_t)(N_NODES + 1) * D * 2);         // fp16 h table

  // prep: deg zero + x->bf16/fp16 + W->bf16 + sentinel rows + ell sentinel fill
  k_prep<<<6002, 256, 0, stream>>>(x, xb, hb, xh, hh, deg, ell,
                                   W1l, W1r, W2l, W2r, w1lb, w1rb, w2lb, w2rb);

  // ELL adjacency (count + fill fused; no scan)
  k_fillell<<<(N_EDGES + 255) / 256, 256, 0, stream>>>(srcp, dstp, deg, ell);

  // layer 1: mean1 = agg_fp16(xh) -> mb ; h = relu(mean1@W1l^T + b1 + xb@W1r^T) -> hb + hh
  k_agg<<<N_NODES / 32, 256, 0, stream>>>((const uint4*)xh, deg, ell, (uint4*)mb);
  k_gemm<<<N_NODES / 32, 64, 0, stream>>>(mb, xb, w1lb, w1rb, b1l, hb, hh, nullptr, 1);

  // layer 2: mean2 = agg_fp16(hh) -> mb ; out(fp32) = mean2@W2l^T + b2 + hb@W2r^T
  k_agg<<<N_NODES / 32, 256, 0, stream>>>((const uint4*)hh, deg, ell, (uint4*)mb);
  k_gemm<<<N_NODES / 32, 64, 0, stream>>>(mb, hb, w2lb, w2rb, b2l, nullptr, nullptr,
                                          (float*)d_out, 0);
}

// Round 20
// 108.278 us; speedup vs baseline: 1.1556x; 1.1556x over previous
//
#include <hip/hip_runtime.h>

#define N_NODES 40000
#define N_EDGES 640000
#define D 128
#define ELLW 48        // max degree headroom (Binomial max ~35); multiple of 16
#define SENT 40000     // sentinel node index -> zeroed feature row

typedef __attribute__((ext_vector_type(8))) short short8;
typedef __attribute__((ext_vector_type(4))) float f32x4;
typedef __attribute__((ext_vector_type(2))) float f32x2;

__device__ __forceinline__ unsigned short f2bf(float f) {
  unsigned int u = __float_as_uint(f);
  u += 0x7fffu + ((u >> 16) & 1u);   // round-to-nearest-even
  return (unsigned short)(u >> 16);
}

// pack 4 floats -> 4 x fp8 e4m3 (one uint), HW cvt
__device__ __forceinline__ unsigned int pk_fp8x4(float a, float b, float c, float d) {
  int v = __builtin_amdgcn_cvt_pk_fp8_f32(a, b, 0, false);
  v = __builtin_amdgcn_cvt_pk_fp8_f32(c, d, v, true);
  return (unsigned int)v;
}
// accumulate 4 fp8 (one uint) into a[0..3]
__device__ __forceinline__ void acc_fp8x4(unsigned int u, float* a) {
  f32x2 p0 = __builtin_amdgcn_cvt_pk_f32_fp8(u, false);
  f32x2 p1 = __builtin_amdgcn_cvt_pk_f32_fp8(u, true);
  a[0] += p0[0]; a[1] += p0[1]; a[2] += p1[0]; a[3] += p1[1];
}

// ---------------- k0: deg zero + ell sentinel fill + fp8 sentinel rows ------------
// Small fast kernel so the heavy converts and fillell can share ONE dispatch after.
// blocks [0,938): ell fill (240,000 uint4); block 938: deg zero + sentinel rows.
__global__ void k_init(int* __restrict__ deg, unsigned short* __restrict__ ell,
                       unsigned char* __restrict__ xf8, unsigned char* __restrict__ hf8) {
  int b = blockIdx.x;
  int tid = threadIdx.x;
  if (b < 938) {                        // ell sentinel fill: 240,000 uint4
    int i = b * 256 + tid;
    if (i < N_NODES * ELLW / 8) {
      unsigned int sv = (SENT & 0xffffu) | ((unsigned int)SENT << 16);
      uint4 q; q.x = sv; q.y = sv; q.z = sv; q.w = sv;
      ((uint4*)ell)[i] = q;
    }
  } else {                              // deg zero (10,000 int4) spread over 40 blocks
    int i = (b - 938) * 256 + tid;
    if (i < N_NODES / 4) ((int4*)deg)[i] = make_int4(0, 0, 0, 0);
    if (b == 938) {
      if (tid < 32)      ((unsigned int*)(xf8 + (size_t)SENT * D))[tid] = 0u;
      else if (tid < 64) ((unsigned int*)(hf8 + (size_t)SENT * D))[tid - 32] = 0u;
    }
  }
}

// ---------------- k1: fillell + x->bf16/fp8 + W->bf16, one dispatch ---------------
// fillell blocks FIRST (latency/atomic-bound) so they overlap the streaming
// converts. fillell depends only on k0 (deg=0, ell=SENT); converts are independent.
// blocks [0,2500): fillell; [2500,7500): x converts; [7500,7564): W converts.
__global__ void k_prep(const int* __restrict__ src, const int* __restrict__ dst,
                       int* __restrict__ deg, unsigned short* __restrict__ ell,
                       const float* __restrict__ x, unsigned short* __restrict__ xb,
                       unsigned char* __restrict__ xf8,
                       const float* __restrict__ w0, const float* __restrict__ w1,
                       const float* __restrict__ w2, const float* __restrict__ w3,
                       unsigned short* __restrict__ o0, unsigned short* __restrict__ o1,
                       unsigned short* __restrict__ o2, unsigned short* __restrict__ o3) {
  int b = blockIdx.x;
  int tid = threadIdx.x;
  if (b < 2500) {                       // fillell: 640,000 edges
    int e = b * 256 + tid;
    int d = dst[e];
    int pos = atomicAdd(&deg[d], 1);
    if (pos < ELLW) ell[(size_t)d * ELLW + pos] = (unsigned short)src[e];
  } else if (b < 7500) {                // x converts: 1,280,000 float4 groups
    int i = (b - 2500) * 256 + tid;
    float4 v = ((const float4*)x)[i];
    unsigned int lo = (unsigned int)f2bf(v.x) | ((unsigned int)f2bf(v.y) << 16);
    unsigned int hi = (unsigned int)f2bf(v.z) | ((unsigned int)f2bf(v.w) << 16);
    ((uint2*)xb)[i] = make_uint2(lo, hi);
    ((unsigned int*)xf8)[i] = pk_fp8x4(v.x, v.y, v.z, v.w);
  } else {                              // W converts: 4 * 4096 float4 groups
    int i = (b - 7500) * 256 + tid;
    int m = i >> 12, j = i & 4095;
    const float* s = (m == 0) ? w0 : (m == 1) ? w1 : (m == 2) ? w2 : w3;
    unsigned short* o = (m == 0) ? o0 : (m == 1) ? o1 : (m == 2) ? o2 : o3;
    float4 v = ((const float4*)s)[j];
    unsigned int lo = (unsigned int)f2bf(v.x) | ((unsigned int)f2bf(v.y) << 16);
    unsigned int hi = (unsigned int)f2bf(v.z) | ((unsigned int)f2bf(v.w) << 16);
    ((uint2*)o)[j] = make_uint2(lo, hi);
  }
}

// ---------------- aggregation v8 (r15 winner, FROZEN): transposed fp8 -------------
// 8 lanes own one node (lane chunk s = cols [16s,16s+16) as one uint4 of fp8);
// 8 nodes per wave -> 5000 waves. Zero cross-lane reduce. 4 gathers in flight
// (under the VGPR=64 occupancy cliff; 8-deep regressed 2x in r17). fp8 rows =
// 1 gather instruction per 8 neighbor rows - the instruction-count minimum
// (fp16's 2x instructions regressed 19us in r19).
__global__ void k_agg(const uint4* __restrict__ t8, const int* __restrict__ deg,
                      const unsigned short* __restrict__ ell, uint4* __restrict__ mean4) {
  int node = blockIdx.x * 32 + (threadIdx.x >> 3);   // 32 nodes per 256-thread block
  int s = threadIdx.x & 7;                           // uint4 chunk within 128B fp8 row
  int d = deg[node];
  int cnt = d < ELLW ? d : ELLW;
  int cntp = (cnt + 3) & ~3;                         // sentinel-padded to mult of 4
  const unsigned short* row = ell + (size_t)node * ELLW;
  float a[16];
#pragma unroll
  for (int i = 0; i < 16; ++i) a[i] = 0.f;
  for (int e = 0; e < cntp; e += 4) {
    int i0 = row[e], i1 = row[e + 1], i2 = row[e + 2], i3 = row[e + 3];
    uint4 v0 = t8[(size_t)i0 * 8 + s];               // 4 independent gathers in flight
    uint4 v1 = t8[(size_t)i1 * 8 + s];
    uint4 v2 = t8[(size_t)i2 * 8 + s];
    uint4 v3 = t8[(size_t)i3 * 8 + s];
    acc_fp8x4(v0.x, a + 0); acc_fp8x4(v0.y, a + 4);
    acc_fp8x4(v0.z, a + 8); acc_fp8x4(v0.w, a + 12);
    acc_fp8x4(v1.x, a + 0); acc_fp8x4(v1.y, a + 4);
    acc_fp8x4(v1.z, a + 8); acc_fp8x4(v1.w, a + 12);
    acc_fp8x4(v2.x, a + 0); acc_fp8x4(v2.y, a + 4);
    acc_fp8x4(v2.z, a + 8); acc_fp8x4(v2.w, a + 12);
    acc_fp8x4(v3.x, a + 0); acc_fp8x4(v3.y, a + 4);
    acc_fp8x4(v3.z, a + 8); acc_fp8x4(v3.w, a + 12);
  }
  float inv = 1.0f / (float)(d > 1 ? d : 1);
#pragma unroll
  for (int i = 0; i < 16; ++i) a[i] *= inv;
  uint4 o0, o1;
  o0.x = (unsigned int)f2bf(a[0]) | ((unsigned int)f2bf(a[1]) << 16);
  o0.y = (unsigned int)f2bf(a[2]) | ((unsigned int)f2bf(a[3]) << 16);
  o0.z = (unsigned int)f2bf(a[4]) | ((unsigned int)f2bf(a[5]) << 16);
  o0.w = (unsigned int)f2bf(a[6]) | ((unsigned int)f2bf(a[7]) << 16);
  o1.x = (unsigned int)f2bf(a[8]) | ((unsigned int)f2bf(a[9]) << 16);
  o1.y = (unsigned int)f2bf(a[10]) | ((unsigned int)f2bf(a[11]) << 16);
  o1.z = (unsigned int)f2bf(a[12]) | ((unsigned int)f2bf(a[13]) << 16);
  o1.w = (unsigned int)f2bf(a[14]) | ((unsigned int)f2bf(a[15]) << 16);
  mean4[(size_t)node * 16 + s * 2] = o0;
  mean4[(size_t)node * 16 + s * 2 + 1] = o1;
}

// ---------------- dual bf16-MFMA GEMM (FROZEN): 1 wave = 32 rows, no LDS ----------
__global__ __launch_bounds__(64) void k_gemm(
    const unsigned short* __restrict__ Al, const unsigned short* __restrict__ Ar,
    const unsigned short* __restrict__ Wl, const unsigned short* __restrict__ Wr,
    const float* __restrict__ bias,
    unsigned short* __restrict__ out_bf, unsigned char* __restrict__ out_f8,
    float* __restrict__ out_f, int relu_bf16) {
  const int lane = threadIdx.x;
  const int m0 = blockIdx.x * 32;
  const int ml = lane & 15;      // row within m-subtile / col within n-tile
  const int kg = lane >> 4;      // k-group of 8
  const unsigned short* al0 = Al + (size_t)(m0 + ml) * 128 + kg * 8;
  const unsigned short* ar0 = Ar + (size_t)(m0 + ml) * 128 + kg * 8;
  const unsigned short* al1 = al0 + 16 * 128;
  const unsigned short* ar1 = ar0 + 16 * 128;
  const unsigned short* wl_p = Wl + (size_t)ml * 128 + kg * 8;
  const unsigned short* wr_p = Wr + (size_t)ml * 128 + kg * 8;

  f32x4 acc[2][8];
#pragma unroll
  for (int mt = 0; mt < 2; ++mt)
#pragma unroll
    for (int nt = 0; nt < 8; ++nt) acc[mt][nt] = 0;

#pragma unroll
  for (int kt = 0; kt < 4; ++kt) {
    short8 a0l = *(const short8*)(al0 + kt * 32);
    short8 a0r = *(const short8*)(ar0 + kt * 32);
    short8 a1l = *(const short8*)(al1 + kt * 32);
    short8 a1r = *(const short8*)(ar1 + kt * 32);
#pragma unroll
    for (int nt = 0; nt < 8; ++nt) {
      short8 b_l = *(const short8*)(wl_p + nt * 2048 + kt * 32);
      short8 b_r = *(const short8*)(wr_p + nt * 2048 + kt * 32);
      acc[0][nt] = __builtin_amdgcn_mfma_f32_16x16x32_bf16(a0l, b_l, acc[0][nt], 0, 0, 0);
      acc[0][nt] = __builtin_amdgcn_mfma_f32_16x16x32_bf16(a0r, b_r, acc[0][nt], 0, 0, 0);
      acc[1][nt] = __builtin_amdgcn_mfma_f32_16x16x32_bf16(a1l, b_l, acc[1][nt], 0, 0, 0);
      acc[1][nt] = __builtin_amdgcn_mfma_f32_16x16x32_bf16(a1r, b_r, acc[1][nt], 0, 0, 0);
    }
  }

#pragma unroll
  for (int mt = 0; mt < 2; ++mt) {
    const int orow = m0 + mt * 16 + kg * 4;   // + r
#pragma unroll
    for (int nt = 0; nt < 8; ++nt) {
      int col = nt * 16 + ml;
      float b = bias[col];
#pragma unroll
      for (int r = 0; r < 4; ++r) {
        float o = acc[mt][nt][r] + b;
        if (relu_bf16) {
          o = fmaxf(o, 0.f);
          out_bf[(size_t)(orow + r) * 128 + col] = f2bf(o);
          unsigned int p8 = (unsigned int)__builtin_amdgcn_cvt_pk_fp8_f32(o, o, 0, false);
          out_f8[(size_t)(orow + r) * 128 + col] = (unsigned char)(p8 & 0xffu);
        } else {
          out_f[(size_t)(orow + r) * 128 + col] = o;
        }
      }
    }
  }
}

extern "C" void kernel_launch(void* const* d_in, const int* in_sizes, int n_in,
                              void* d_out, int out_size, void* d_ws, size_t ws_size,
                              hipStream_t stream) {
  const float* x   = (const float*)d_in[0];
  const int*   ei  = (const int*)d_in[1];
  const float* W1l = (const float*)d_in[2];
  const float* b1l = (const float*)d_in[3];
  const float* W1r = (const float*)d_in[4];
  const float* W2l = (const float*)d_in[5];
  const float* b2l = (const float*)d_in[6];
  const float* W2r = (const float*)d_in[7];
  const int* srcp = ei;
  const int* dstp = ei + N_EDGES;

  char* ws = (char*)d_ws;
  size_t off = 0;
  auto alloc = [&](size_t bytes) {
    void* p = ws + off;
    off = (off + bytes + 255) & ~(size_t)255;
    return p;
  };
  int* deg             = (int*)alloc((size_t)N_NODES * 4);
  unsigned short* ell  = (unsigned short*)alloc((size_t)N_NODES * ELLW * 2);
  unsigned short* w1lb = (unsigned short*)alloc((size_t)D * D * 2);
  unsigned short* w1rb = (unsigned short*)alloc((size_t)D * D * 2);
  unsigned short* w2lb = (unsigned short*)alloc((size_t)D * D * 2);
  unsigned short* w2rb = (unsigned short*)alloc((size_t)D * D * 2);
  unsigned short* xb   = (unsigned short*)alloc((size_t)(N_NODES + 1) * D * 2); // + sentinel
  unsigned short* mb   = (unsigned short*)alloc((size_t)N_NODES * D * 2);
  unsigned short* hb   = (unsigned short*)alloc((size_t)(N_NODES + 1) * D * 2); // + sentinel
  unsigned char* xf8   = (unsigned char*)alloc((size_t)(N_NODES + 1) * D);      // fp8 x table
  unsigned char* hf8   = (unsigned char*)alloc((size_t)(N_NODES + 1) * D);      // fp8 h table

  // k0: deg zero + ell sentinel fill + fp8 sentinel rows (~2us)
  k_init<<<978, 256, 0, stream>>>(deg, ell, xf8, hf8);

  // k1: fillell (overlapped) + x->bf16/fp8 + W->bf16, one dispatch
  k_prep<<<7564, 256, 0, stream>>>(srcp, dstp, deg, ell, x, xb, xf8,
                                   W1l, W1r, W2l, W2r, w1lb, w1rb, w2lb, w2rb);

  // layer 1: mean1 = agg_fp8(xf8) -> mb ; h = relu(mean1@W1l^T + b1 + xb@W1r^T) -> hb + hf8
  k_agg<<<N_NODES / 32, 256, 0, stream>>>((const uint4*)xf8, deg, ell, (uint4*)mb);
  k_gemm<<<N_NODES / 32, 64, 0, stream>>>(mb, xb, w1lb, w1rb, b1l, hb, hf8, nullptr, 1);

  // layer 2: mean2 = agg_fp8(hf8) -> mb ; out(fp32) = mean2@W2l^T + b2 + hb@W2r^T
  k_agg<<<N_NODES / 32, 256, 0, stream>>>((const uint4*)hf8, deg, ell, (uint4*)mb);
  k_gemm<<<N_NODES / 32, 64, 0, stream>>>(mb, hb, w2lb, w2rb, b2l, nullptr, nullptr,
                                          (float*)d_out, 0);
}

// Round 21
// 106.185 us; speedup vs baseline: 1.1784x; 1.0197x over previous
//
#include <hip/hip_runtime.h>

#define N_NODES 40000
#define N_EDGES 640000
#define D 128
#define ELLW 48        // max degree headroom (Binomial max ~35); multiple of 16
#define SENT 40000     // sentinel node index -> zeroed feature row

typedef __attribute__((ext_vector_type(8))) short short8;
typedef __attribute__((ext_vector_type(4))) float f32x4;
typedef __attribute__((ext_vector_type(2))) float f32x2;

__device__ __forceinline__ unsigned short f2bf(float f) {
  unsigned int u = __float_as_uint(f);
  u += 0x7fffu + ((u >> 16) & 1u);   // round-to-nearest-even
  return (unsigned short)(u >> 16);
}

// pack 4 floats -> 4 x fp8 e4m3 (one uint), HW cvt
__device__ __forceinline__ unsigned int pk_fp8x4(float a, float b, float c, float d) {
  int v = __builtin_amdgcn_cvt_pk_fp8_f32(a, b, 0, false);
  v = __builtin_amdgcn_cvt_pk_fp8_f32(c, d, v, true);
  return (unsigned int)v;
}
// accumulate 4 fp8 (one uint) into a[0..3]
__device__ __forceinline__ void acc_fp8x4(unsigned int u, float* a) {
  f32x2 p0 = __builtin_amdgcn_cvt_pk_f32_fp8(u, false);
  f32x2 p1 = __builtin_amdgcn_cvt_pk_f32_fp8(u, true);
  a[0] += p0[0]; a[1] += p0[1]; a[2] += p1[0]; a[3] += p1[1];
}

// ---------------- prep: deg zero + x->bf16 + x->fp8 + W->bf16 + ell sentinel ------
// blocks [0,5000): x converts (1,280,000 float4 groups) + deg zero
// blocks [5000,5064): W converts; block 5000 also zeroes all sentinel rows
// blocks [5064,6002): fill ell with SENT (240,000 uint4)
__global__ void k_prep(const float* __restrict__ x, unsigned short* __restrict__ xb,
                       unsigned short* __restrict__ hb,
                       unsigned char* __restrict__ xf8, unsigned char* __restrict__ hf8,
                       int* __restrict__ deg, unsigned short* __restrict__ ell,
                       const float* __restrict__ w0, const float* __restrict__ w1,
                       const float* __restrict__ w2, const float* __restrict__ w3,
                       unsigned short* __restrict__ o0, unsigned short* __restrict__ o1,
                       unsigned short* __restrict__ o2, unsigned short* __restrict__ o3) {
  int b = blockIdx.x;
  int tid = threadIdx.x;
  if (b < 5000) {                       // x converts (+ deg zero)
    int i = b * 256 + tid;              // i < 1,280,000 exactly
    if (i < N_NODES / 4) ((int4*)deg)[i] = make_int4(0, 0, 0, 0);
    float4 v = ((const float4*)x)[i];
    unsigned int lo = (unsigned int)f2bf(v.x) | ((unsigned int)f2bf(v.y) << 16);
    unsigned int hi = (unsigned int)f2bf(v.z) | ((unsigned int)f2bf(v.w) << 16);
    ((uint2*)xb)[i] = make_uint2(lo, hi);
    ((unsigned int*)xf8)[i] = pk_fp8x4(v.x, v.y, v.z, v.w);
  } else if (b < 5064) {                // W converts: 4 * 4096 float4 groups
    if (b == 5000) {                    // zero sentinel rows
      if (tid < 64) {                   // xb/hb: 128 bf16 = 64 uint each
        ((unsigned int*)(xb + (size_t)SENT * D))[tid] = 0u;
        ((unsigned int*)(hb + (size_t)SENT * D))[tid] = 0u;
      } else if (tid < 96) {            // xf8: 128 B = 32 uint
        ((unsigned int*)(xf8 + (size_t)SENT * D))[tid - 64] = 0u;
      } else if (tid < 128) {           // hf8
        ((unsigned int*)(hf8 + (size_t)SENT * D))[tid - 96] = 0u;
      }
    }
    int i = (b - 5000) * 256 + tid;
    int m = i >> 12, j = i & 4095;
    const float* s = (m == 0) ? w0 : (m == 1) ? w1 : (m == 2) ? w2 : w3;
    unsigned short* o = (m == 0) ? o0 : (m == 1) ? o1 : (m == 2) ? o2 : o3;
    float4 v = ((const float4*)s)[j];
    unsigned int lo = (unsigned int)f2bf(v.x) | ((unsigned int)f2bf(v.y) << 16);
    unsigned int hi = (unsigned int)f2bf(v.z) | ((unsigned int)f2bf(v.w) << 16);
    ((uint2*)o)[j] = make_uint2(lo, hi);
  } else {                              // ell sentinel fill: 240,000 uint4
    int i = (b - 5064) * 256 + tid;
    if (i < N_NODES * ELLW / 8) {
      unsigned int sv = (SENT & 0xffffu) | ((unsigned int)SENT << 16);
      uint4 q; q.x = sv; q.y = sv; q.z = sv; q.w = sv;
      ((uint4*)ell)[i] = q;
    }
  }
}

// ---------------- ELL build: count + fill in ONE kernel (no scan) ----------------
__global__ void k_fillell(const int* __restrict__ src, const int* __restrict__ dst,
                          int* __restrict__ deg, unsigned short* __restrict__ ell) {
  int e = blockIdx.x * 256 + threadIdx.x;
  if (e < N_EDGES) {
    int d = dst[e];
    int pos = atomicAdd(&deg[d], 1);
    if (pos < ELLW) ell[(size_t)d * ELLW + pos] = (unsigned short)src[e];
  }
}

// ---------------- aggregation v8 (FROZEN r15 winner): transposed fp8 --------------
// 8 lanes own one node (lane chunk s = cols [16s,16s+16) as one uint4 of fp8);
// 8 nodes per wave -> 5000 waves. Zero cross-lane reduce. 4 gathers in flight
// (under the VGPR=64 occupancy cliff; 8-deep regressed 2x in r17). fp8 rows =
// 1 gather instruction per 8 neighbor rows - the instruction-count minimum
// (fp16's 2x instructions regressed 19us in r19; line count is a non-factor, r14).
__global__ void k_agg(const uint4* __restrict__ t8, const int* __restrict__ deg,
                      const unsigned short* __restrict__ ell, uint4* __restrict__ mean4) {
  int node = blockIdx.x * 32 + (threadIdx.x >> 3);   // 32 nodes per 256-thread block
  int s = threadIdx.x & 7;                           // uint4 chunk within 128B fp8 row
  int d = deg[node];
  int cnt = d < ELLW ? d : ELLW;
  int cntp = (cnt + 3) & ~3;                         // sentinel-padded to mult of 4
  const unsigned short* row = ell + (size_t)node * ELLW;
  float a[16];
#pragma unroll
  for (int i = 0; i < 16; ++i) a[i] = 0.f;
  for (int e = 0; e < cntp; e += 4) {
    int i0 = row[e], i1 = row[e + 1], i2 = row[e + 2], i3 = row[e + 3];
    uint4 v0 = t8[(size_t)i0 * 8 + s];               // 4 independent gathers in flight
    uint4 v1 = t8[(size_t)i1 * 8 + s];
    uint4 v2 = t8[(size_t)i2 * 8 + s];
    uint4 v3 = t8[(size_t)i3 * 8 + s];
    acc_fp8x4(v0.x, a + 0); acc_fp8x4(v0.y, a + 4);
    acc_fp8x4(v0.z, a + 8); acc_fp8x4(v0.w, a + 12);
    acc_fp8x4(v1.x, a + 0); acc_fp8x4(v1.y, a + 4);
    acc_fp8x4(v1.z, a + 8); acc_fp8x4(v1.w, a + 12);
    acc_fp8x4(v2.x, a + 0); acc_fp8x4(v2.y, a + 4);
    acc_fp8x4(v2.z, a + 8); acc_fp8x4(v2.w, a + 12);
    acc_fp8x4(v3.x, a + 0); acc_fp8x4(v3.y, a + 4);
    acc_fp8x4(v3.z, a + 8); acc_fp8x4(v3.w, a + 12);
  }
  float inv = 1.0f / (float)(d > 1 ? d : 1);
#pragma unroll
  for (int i = 0; i < 16; ++i) a[i] *= inv;
  uint4 o0, o1;
  o0.x = (unsigned int)f2bf(a[0]) | ((unsigned int)f2bf(a[1]) << 16);
  o0.y = (unsigned int)f2bf(a[2]) | ((unsigned int)f2bf(a[3]) << 16);
  o0.z = (unsigned int)f2bf(a[4]) | ((unsigned int)f2bf(a[5]) << 16);
  o0.w = (unsigned int)f2bf(a[6]) | ((unsigned int)f2bf(a[7]) << 16);
  o1.x = (unsigned int)f2bf(a[8]) | ((unsigned int)f2bf(a[9]) << 16);
  o1.y = (unsigned int)f2bf(a[10]) | ((unsigned int)f2bf(a[11]) << 16);
  o1.z = (unsigned int)f2bf(a[12]) | ((unsigned int)f2bf(a[13]) << 16);
  o1.w = (unsigned int)f2bf(a[14]) | ((unsigned int)f2bf(a[15]) << 16);
  mean4[(size_t)node * 16 + s * 2] = o0;
  mean4[(size_t)node * 16 + s * 2 + 1] = o1;
}

// ---------------- dual bf16-MFMA GEMM (FROZEN): 1 wave = 32 rows, no LDS ----------
// relu path additionally emits the fp8 copy of h for the next layer's gather.
__global__ __launch_bounds__(64) void k_gemm(
    const unsigned short* __restrict__ Al, const unsigned short* __restrict__ Ar,
    const unsigned short* __restrict__ Wl, const unsigned short* __restrict__ Wr,
    const float* __restrict__ bias,
    unsigned short* __restrict__ out_bf, unsigned char* __restrict__ out_f8,
    float* __restrict__ out_f, int relu_bf16) {
  const int lane = threadIdx.x;
  const int m0 = blockIdx.x * 32;
  const int ml = lane & 15;      // row within m-subtile / col within n-tile
  const int kg = lane >> 4;      // k-group of 8
  const unsigned short* al0 = Al + (size_t)(m0 + ml) * 128 + kg * 8;
  const unsigned short* ar0 = Ar + (size_t)(m0 + ml) * 128 + kg * 8;
  const unsigned short* al1 = al0 + 16 * 128;
  const unsigned short* ar1 = ar0 + 16 * 128;
  const unsigned short* wl_p = Wl + (size_t)ml * 128 + kg * 8;
  const unsigned short* wr_p = Wr + (size_t)ml * 128 + kg * 8;

  f32x4 acc[2][8];
#pragma unroll
  for (int mt = 0; mt < 2; ++mt)
#pragma unroll
    for (int nt = 0; nt < 8; ++nt) acc[mt][nt] = 0;

#pragma unroll
  for (int kt = 0; kt < 4; ++kt) {
    short8 a0l = *(const short8*)(al0 + kt * 32);
    short8 a0r = *(const short8*)(ar0 + kt * 32);
    short8 a1l = *(const short8*)(al1 + kt * 32);
    short8 a1r = *(const short8*)(ar1 + kt * 32);
#pragma unroll
    for (int nt = 0; nt < 8; ++nt) {
      short8 b_l = *(const short8*)(wl_p + nt * 2048 + kt * 32);
      short8 b_r = *(const short8*)(wr_p + nt * 2048 + kt * 32);
      acc[0][nt] = __builtin_amdgcn_mfma_f32_16x16x32_bf16(a0l, b_l, acc[0][nt], 0, 0, 0);
      acc[0][nt] = __builtin_amdgcn_mfma_f32_16x16x32_bf16(a0r, b_r, acc[0][nt], 0, 0, 0);
      acc[1][nt] = __builtin_amdgcn_mfma_f32_16x16x32_bf16(a1l, b_l, acc[1][nt], 0, 0, 0);
      acc[1][nt] = __builtin_amdgcn_mfma_f32_16x16x32_bf16(a1r, b_r, acc[1][nt], 0, 0, 0);
    }
  }

#pragma unroll
  for (int mt = 0; mt < 2; ++mt) {
    const int orow = m0 + mt * 16 + kg * 4;   // + r
#pragma unroll
    for (int nt = 0; nt < 8; ++nt) {
      int col = nt * 16 + ml;
      float b = bias[col];
#pragma unroll
      for (int r = 0; r < 4; ++r) {
        float o = acc[mt][nt][r] + b;
        if (relu_bf16) {
          o = fmaxf(o, 0.f);
          out_bf[(size_t)(orow + r) * 128 + col] = f2bf(o);
          unsigned int p8 = (unsigned int)__builtin_amdgcn_cvt_pk_fp8_f32(o, o, 0, false);
          out_f8[(size_t)(orow + r) * 128 + col] = (unsigned char)(p8 & 0xffu);
        } else {
          out_f[(size_t)(orow + r) * 128 + col] = o;
        }
      }
    }
  }
}

extern "C" void kernel_launch(void* const* d_in, const int* in_sizes, int n_in,
                              void* d_out, int out_size, void* d_ws, size_t ws_size,
                              hipStream_t stream) {
  const float* x   = (const float*)d_in[0];
  const int*   ei  = (const int*)d_in[1];
  const float* W1l = (const float*)d_in[2];
  const float* b1l = (const float*)d_in[3];
  const float* W1r = (const float*)d_in[4];
  const float* W2l = (const float*)d_in[5];
  const float* b2l = (const float*)d_in[6];
  const float* W2r = (const float*)d_in[7];
  const int* srcp = ei;
  const int* dstp = ei + N_EDGES;

  char* ws = (char*)d_ws;
  size_t off = 0;
  auto alloc = [&](size_t bytes) {
    void* p = ws + off;
    off = (off + bytes + 255) & ~(size_t)255;
    return p;
  };
  int* deg             = (int*)alloc((size_t)N_NODES * 4);
  unsigned short* ell  = (unsigned short*)alloc((size_t)N_NODES * ELLW * 2);
  unsigned short* w1lb = (unsigned short*)alloc((size_t)D * D * 2);
  unsigned short* w1rb = (unsigned short*)alloc((size_t)D * D * 2);
  unsigned short* w2lb = (unsigned short*)alloc((size_t)D * D * 2);
  unsigned short* w2rb = (unsigned short*)alloc((size_t)D * D * 2);
  unsigned short* xb   = (unsigned short*)alloc((size_t)(N_NODES + 1) * D * 2); // + sentinel
  unsigned short* mb   = (unsigned short*)alloc((size_t)N_NODES * D * 2);
  unsigned short* hb   = (unsigned short*)alloc((size_t)(N_NODES + 1) * D * 2); // + sentinel
  unsigned char* xf8   = (unsigned char*)alloc((size_t)(N_NODES + 1) * D);      // fp8 x table
  unsigned char* hf8   = (unsigned char*)alloc((size_t)(N_NODES + 1) * D);      // fp8 h table

  // prep: deg zero + x->bf16/fp8 + W->bf16 + sentinel rows + ell sentinel fill
  k_prep<<<6002, 256, 0, stream>>>(x, xb, hb, xf8, hf8, deg, ell,
                                   W1l, W1r, W2l, W2r, w1lb, w1rb, w2lb, w2rb);

  // ELL adjacency (count + fill fused; no scan)
  k_fillell<<<(N_EDGES + 255) / 256, 256, 0, stream>>>(srcp, dstp, deg, ell);

  // layer 1: mean1 = agg_fp8(xf8) -> mb ; h = relu(mean1@W1l^T + b1 + xb@W1r^T) -> hb + hf8
  k_agg<<<N_NODES / 32, 256, 0, stream>>>((const uint4*)xf8, deg, ell, (uint4*)mb);
  k_gemm<<<N_NODES / 32, 64, 0, stream>>>(mb, xb, w1lb, w1rb, b1l, hb, hf8, nullptr, 1);

  // layer 2: mean2 = agg_fp8(hf8) -> mb ; out(fp32) = mean2@W2l^T + b2 + hb@W2r^T
  k_agg<<<N_NODES / 32, 256, 0, stream>>>((const uint4*)hf8, deg, ell, (uint4*)mb);
  k_gemm<<<N_NODES / 32, 64, 0, stream>>>(mb, hb, w2lb, w2rb, b2l, nullptr, nullptr,
                                          (float*)d_out, 0);
}